// Round 7
// baseline (1964.257 us; speedup 1.0000x reference)
//
#include <hip/hip_runtime.h>
#include <hip/hip_bf16.h>
#include <math.h>

#define F_IN 256
#define F_OUT 64
#define NEG_SLOPE 0.2f
#define GROWS 16        // rows per GEMM block
#define NREP 8          // XCD replicas for cursors/counters
#define BROWS 128       // rows per bucket
#define EPB 4096        // edges per hist/scatter block (256 thr x 16)

// ---------------------------------------------------------------------------
// GEMM seq[N,256] @ W[256,64] -> fts[N,64], fused f1/f2.
// ---------------------------------------------------------------------------
__global__ __launch_bounds__(256) void gemm_f12_kernel(
    const float* __restrict__ seq, const float* __restrict__ W,
    const float* __restrict__ a1, const float* __restrict__ b1,
    const float* __restrict__ a2, const float* __restrict__ b2,
    float* __restrict__ fts, float* __restrict__ f1, float* __restrict__ f2, int n)
{
    __shared__ __align__(16) float sseq[GROWS][F_IN];   // 16 KB

    const int tid = threadIdx.x;
    const int r0  = blockIdx.x * GROWS;
    if (r0 >= n) return;

    const int rows = (n - r0 < GROWS) ? (n - r0) : GROWS;
    const int lim4 = rows * (F_IN / 4);
    const float4* src = (const float4*)(seq + (size_t)r0 * F_IN);
    float4* dst = (float4*)(&sseq[0][0]);
    for (int i = tid; i < lim4; i += 256) dst[i] = src[i];
    __syncthreads();

    const int lane = tid & 63;
    const int wv   = tid >> 6;

    float acc[4] = {0.f, 0.f, 0.f, 0.f};
    for (int k = 0; k < F_IN; ++k) {
        float w = W[k * F_OUT + lane];
        #pragma unroll
        for (int i = 0; i < 4; ++i)
            acc[i] = fmaf(sseq[wv * 4 + i][k], w, acc[i]);
    }

    const float va1 = a1[lane], va2 = a2[lane];
    const float vb1 = b1[0],    vb2 = b2[0];

    #pragma unroll
    for (int i = 0; i < 4; ++i) {
        int r = r0 + wv * 4 + i;
        if (r < n) {
            fts[(size_t)r * F_OUT + lane] = acc[i];
            float p1 = acc[i] * va1;
            float p2 = acc[i] * va2;
            #pragma unroll
            for (int m = 1; m < 64; m <<= 1) {
                p1 += __shfl_xor(p1, m, 64);
                p2 += __shfl_xor(p2, m, 64);
            }
            if (lane == 0) {
                f1[r] = p1 + vb1;
                f2[r] = p2 + vb2;
            }
        }
    }
}

// ---------------------------------------------------------------------------
// Pass A: bucket histogram, LDS pre-aggregated, flushed to XCD replica bid&7.
// ---------------------------------------------------------------------------
__global__ __launch_bounds__(256) void bucket_hist_kernel(
    const int* __restrict__ er, unsigned* __restrict__ cntB, int nb, int e)
{
    __shared__ unsigned h[1024];
    const int tid = threadIdx.x;
    for (int b = tid; b < 1024; b += 256) h[b] = 0u;
    __syncthreads();

    const int base = blockIdx.x * EPB;
    #pragma unroll
    for (int i = 0; i < 16; ++i) {
        int t = base + i * 256 + tid;
        if (t < e) atomicAdd(&h[er[t] >> 7], 1u);
    }
    __syncthreads();

    const int rep = blockIdx.x & (NREP - 1);
    for (int b = tid; b < nb; b += 256) {
        unsigned c = h[b];
        if (c) atomicAdd(cntB + (size_t)rep * nb + b, c);
    }
}

// ---------------------------------------------------------------------------
// Scan: 1 block, 1024 threads; bucket t gets global start + per-replica
// cursor bases.  nb <= 1024.
// ---------------------------------------------------------------------------
__global__ __launch_bounds__(1024) void bucket_scan_kernel(
    const unsigned* __restrict__ cntB, unsigned* __restrict__ posB,
    unsigned* __restrict__ bstart, int nb, unsigned e)
{
    __shared__ unsigned wsum[16];
    const int tid  = threadIdx.x;
    const int lane = tid & 63;
    const int wv   = tid >> 6;

    unsigned c[NREP];
    unsigned s = 0;
    if (tid < nb) {
        #pragma unroll
        for (int k = 0; k < NREP; ++k) { c[k] = cntB[(size_t)k * nb + tid]; s += c[k]; }
    }

    unsigned v = s;
    #pragma unroll
    for (int off = 1; off < 64; off <<= 1) {
        unsigned t2 = __shfl_up(v, off, 64);
        if (lane >= off) v += t2;
    }
    if (lane == 63) wsum[wv] = v;
    __syncthreads();
    if (tid == 0) {
        unsigned run = 0;
        #pragma unroll
        for (int w = 0; w < 16; ++w) { unsigned t2 = wsum[w]; wsum[w] = run; run += t2; }
        bstart[nb] = e;
    }
    __syncthreads();

    if (tid < nb) {
        unsigned run = (v - s) + wsum[wv];
        bstart[tid] = run;
        #pragma unroll
        for (int k = 0; k < NREP; ++k) {
            posB[(size_t)k * nb + tid] = run;
            run += c[k];
        }
    }
}

// ---------------------------------------------------------------------------
// Pass B: scatter packed (row_local<<17 | col) into bucket segments.
// Cursor atomics hit this XCD's replica; payload slots for one replica are
// consecutive -> L2 write-combining -> ~one HBM write per line.
// ---------------------------------------------------------------------------
__global__ __launch_bounds__(256) void bucket_scatter_kernel(
    const int* __restrict__ er, const int* __restrict__ ec,
    unsigned* __restrict__ posB, unsigned* __restrict__ payload, int nb, int e)
{
    const int tid  = threadIdx.x;
    const int base = blockIdx.x * EPB;
    const int rep  = blockIdx.x & (NREP - 1);
    #pragma unroll
    for (int i = 0; i < 16; ++i) {
        int t = base + i * 256 + tid;
        if (t < e) {
            int r = er[t];
            int c = ec[t];
            unsigned p = atomicAdd(posB + (size_t)rep * nb + (r >> 7), 1u);
            payload[p] = ((unsigned)(r & (BROWS - 1)) << 17) | (unsigned)c;
        }
    }
}

// ---------------------------------------------------------------------------
// Pass C: bucket SpMM. One block per bucket; 128x64 f32 LDS accumulator
// (ds_add_f32 atomics); recompute ev from f1/f2; fused norm+bias+relu.
// ---------------------------------------------------------------------------
__global__ __launch_bounds__(256) void spmm_bucket_kernel(
    const unsigned* __restrict__ bstart, const unsigned* __restrict__ payload,
    const float* __restrict__ f1, const float* __restrict__ f2,
    const float* __restrict__ fts, const float* __restrict__ bias,
    float* __restrict__ out, int n)
{
    __shared__ float acc[BROWS * F_OUT];   // 32 KB
    __shared__ float evs[BROWS];
    __shared__ float f1s[BROWS];

    const int tid  = threadIdx.x;
    const int lane = tid & 63;
    const int wv   = tid >> 6;
    const int b    = blockIdx.x;
    const int r0   = b * BROWS;
    const int rows = (n - r0 < BROWS) ? (n - r0) : BROWS;

    #pragma unroll
    for (int i = 0; i < BROWS * F_OUT / 256; ++i) acc[tid + i * 256] = 0.f;
    if (tid < BROWS) {
        evs[tid] = 0.f;
        f1s[tid] = (tid < rows) ? f1[r0 + tid] : 0.f;
    }
    __syncthreads();

    const unsigned s0 = bstart[b], s1 = bstart[b + 1];

    for (unsigned base = s0 + (unsigned)wv * 64u; base < s1; base += 256u) {
        int kmax = (int)(s1 - base);
        if (kmax > 64) kmax = 64;

        int   rl = 0, col = 0;
        float ev = 0.f;
        if (lane < kmax) {
            unsigned p = payload[base + lane];
            rl  = (int)(p >> 17);
            col = (int)(p & 0x1FFFFu);
            float l = f1s[rl] + f2[col];
            l = (l > 0.f) ? l : NEG_SLOPE * l;
            ev = __expf(l);
            atomicAdd(&evs[rl], ev);
        }

        for (int j = 0; j < kmax; ++j) {
            int   cj  = __shfl(col, j, 64);
            float ej  = __shfl(ev,  j, 64);
            int   rlj = __shfl(rl,  j, 64);
            atomicAdd(&acc[rlj * F_OUT + lane], ej * fts[(size_t)cj * F_OUT + lane]);
        }
    }
    __syncthreads();

    const int lim = rows * F_OUT;
    for (int idx = tid; idx < lim; idx += 256) {
        int row = idx >> 6;
        int c   = idx & 63;
        float es = evs[row];
        float v  = (es > 0.f) ? (acc[idx] / es) : 0.f;
        v += bias[c];
        out[(size_t)(r0 + row) * F_OUT + c] = fmaxf(v, 0.f);
    }
}

// ---------------------------------------------------------------------------
extern "C" void kernel_launch(void* const* d_in, const int* in_sizes, int n_in,
                              void* d_out, int out_size, void* d_ws, size_t ws_size,
                              hipStream_t stream)
{
    const float* seq  = (const float*)d_in[0];
    const int*   er   = (const int*)  d_in[1];
    const int*   ec   = (const int*)  d_in[2];
    const float* W    = (const float*)d_in[3];
    const float* a1   = (const float*)d_in[4];
    const float* b1   = (const float*)d_in[5];
    const float* a2   = (const float*)d_in[6];
    const float* b2   = (const float*)d_in[7];
    const float* bias = (const float*)d_in[8];

    const int n  = in_sizes[0] / F_IN;
    const int e  = in_sizes[1];
    const int nb = (n + BROWS - 1) / BROWS;       // 782 for N=100000 (<=1024)
    const int eb = (e + EPB - 1) / EPB;           // 782 edge blocks

    char* ws = (char*)d_ws;
    float*    fts     = (float*)ws;    ws += (size_t)n * F_OUT * sizeof(float);   // 25.6 MB
    unsigned* payload = (unsigned*)ws; ws += (size_t)e * sizeof(unsigned);        // 12.8 MB
    float*    f1      = (float*)ws;    ws += (size_t)n * sizeof(float);
    float*    f2      = (float*)ws;    ws += (size_t)n * sizeof(float);
    unsigned* cntB    = (unsigned*)ws; ws += (size_t)NREP * nb * sizeof(unsigned);
    unsigned* posB    = (unsigned*)ws; ws += (size_t)NREP * nb * sizeof(unsigned);
    unsigned* bstart  = (unsigned*)ws; ws += (size_t)(nb + 1) * sizeof(unsigned);

    float* out = (float*)d_out;

    hipMemsetAsync(cntB, 0, (size_t)NREP * nb * sizeof(unsigned), stream);

    gemm_f12_kernel<<<(n + GROWS - 1) / GROWS, 256, 0, stream>>>(
        seq, W, a1, b1, a2, b2, fts, f1, f2, n);

    bucket_hist_kernel<<<eb, 256, 0, stream>>>(er, cntB, nb, e);

    bucket_scan_kernel<<<1, 1024, 0, stream>>>(cntB, posB, bstart, nb, (unsigned)e);

    bucket_scatter_kernel<<<eb, 256, 0, stream>>>(er, ec, posB, payload, nb, e);

    spmm_bucket_kernel<<<nb, 256, 0, stream>>>(
        bstart, payload, f1, f2, fts, bias, out, n);
}

// Round 8
// 643.836 us; speedup vs baseline: 3.0509x; 3.0509x over previous
//
#include <hip/hip_runtime.h>
#include <hip/hip_bf16.h>
#include <math.h>

#define F_IN 256
#define F_OUT 64
#define NEG_SLOPE 0.2f
#define GROWS 16        // rows per GEMM block
#define NREP 8          // XCD replicas for cursors/counters
#define BROWS 128       // rows per bucket
#define EPB 4096        // edges per hist/scatter block (256 thr x 16)

// ---------------------------------------------------------------------------
// GEMM seq[N,256] @ W[256,64] -> fts[N,64], fused f1/f2.
// ---------------------------------------------------------------------------
__global__ __launch_bounds__(256) void gemm_f12_kernel(
    const float* __restrict__ seq, const float* __restrict__ W,
    const float* __restrict__ a1, const float* __restrict__ b1,
    const float* __restrict__ a2, const float* __restrict__ b2,
    float* __restrict__ fts, float* __restrict__ f1, float* __restrict__ f2, int n)
{
    __shared__ __align__(16) float sseq[GROWS][F_IN];   // 16 KB

    const int tid = threadIdx.x;
    const int r0  = blockIdx.x * GROWS;
    if (r0 >= n) return;

    const int rows = (n - r0 < GROWS) ? (n - r0) : GROWS;
    const int lim4 = rows * (F_IN / 4);
    const float4* src = (const float4*)(seq + (size_t)r0 * F_IN);
    float4* dst = (float4*)(&sseq[0][0]);
    for (int i = tid; i < lim4; i += 256) dst[i] = src[i];
    __syncthreads();

    const int lane = tid & 63;
    const int wv   = tid >> 6;

    float acc[4] = {0.f, 0.f, 0.f, 0.f};
    for (int k = 0; k < F_IN; ++k) {
        float w = W[k * F_OUT + lane];
        #pragma unroll
        for (int i = 0; i < 4; ++i)
            acc[i] = fmaf(sseq[wv * 4 + i][k], w, acc[i]);
    }

    const float va1 = a1[lane], va2 = a2[lane];
    const float vb1 = b1[0],    vb2 = b2[0];

    #pragma unroll
    for (int i = 0; i < 4; ++i) {
        int r = r0 + wv * 4 + i;
        if (r < n) {
            fts[(size_t)r * F_OUT + lane] = acc[i];
            float p1 = acc[i] * va1;
            float p2 = acc[i] * va2;
            #pragma unroll
            for (int m = 1; m < 64; m <<= 1) {
                p1 += __shfl_xor(p1, m, 64);
                p2 += __shfl_xor(p2, m, 64);
            }
            if (lane == 0) {
                f1[r] = p1 + vb1;
                f2[r] = p2 + vb2;
            }
        }
    }
}

// ---------------------------------------------------------------------------
// Pass A: bucket histogram, LDS pre-aggregated, flushed to XCD replica bid&7.
// ---------------------------------------------------------------------------
__global__ __launch_bounds__(256) void bucket_hist_kernel(
    const int* __restrict__ er, unsigned* __restrict__ cntB, int nb, int e)
{
    __shared__ unsigned h[1024];
    const int tid = threadIdx.x;
    for (int b = tid; b < 1024; b += 256) h[b] = 0u;
    __syncthreads();

    const int base = blockIdx.x * EPB;
    #pragma unroll
    for (int i = 0; i < 16; ++i) {
        int t = base + i * 256 + tid;
        if (t < e) atomicAdd(&h[er[t] >> 7], 1u);
    }
    __syncthreads();

    const int rep = blockIdx.x & (NREP - 1);
    for (int b = tid; b < nb; b += 256) {
        unsigned c = h[b];
        if (c) atomicAdd(cntB + (size_t)rep * nb + b, c);
    }
}

// ---------------------------------------------------------------------------
// Scan: 1 block, 1024 threads; bucket t gets global start + per-replica
// cursor bases.  nb <= 1024.
// ---------------------------------------------------------------------------
__global__ __launch_bounds__(1024) void bucket_scan_kernel(
    const unsigned* __restrict__ cntB, unsigned* __restrict__ posB,
    unsigned* __restrict__ bstart, int nb, unsigned e)
{
    __shared__ unsigned wsum[16];
    const int tid  = threadIdx.x;
    const int lane = tid & 63;
    const int wv   = tid >> 6;

    unsigned c[NREP];
    unsigned s = 0;
    if (tid < nb) {
        #pragma unroll
        for (int k = 0; k < NREP; ++k) { c[k] = cntB[(size_t)k * nb + tid]; s += c[k]; }
    }

    unsigned v = s;
    #pragma unroll
    for (int off = 1; off < 64; off <<= 1) {
        unsigned t2 = __shfl_up(v, off, 64);
        if (lane >= off) v += t2;
    }
    if (lane == 63) wsum[wv] = v;
    __syncthreads();
    if (tid == 0) {
        unsigned run = 0;
        #pragma unroll
        for (int w = 0; w < 16; ++w) { unsigned t2 = wsum[w]; wsum[w] = run; run += t2; }
        bstart[nb] = e;
    }
    __syncthreads();

    if (tid < nb) {
        unsigned run = (v - s) + wsum[wv];
        bstart[tid] = run;
        #pragma unroll
        for (int k = 0; k < NREP; ++k) {
            posB[(size_t)k * nb + tid] = run;
            run += c[k];
        }
    }
}

// ---------------------------------------------------------------------------
// Pass B: scatter packed (row_local<<17 | col) into bucket segments.
// Cursor atomics hit this XCD's replica; payload slots for one replica are
// consecutive -> L2 write-combining -> ~one HBM write per line.
// ---------------------------------------------------------------------------
__global__ __launch_bounds__(256) void bucket_scatter_kernel(
    const int* __restrict__ er, const int* __restrict__ ec,
    unsigned* __restrict__ posB, unsigned* __restrict__ payload, int nb, int e)
{
    const int tid  = threadIdx.x;
    const int base = blockIdx.x * EPB;
    const int rep  = blockIdx.x & (NREP - 1);
    #pragma unroll
    for (int i = 0; i < 16; ++i) {
        int t = base + i * 256 + tid;
        if (t < e) {
            int r = er[t];
            int c = ec[t];
            unsigned p = atomicAdd(posB + (size_t)rep * nb + (r >> 7), 1u);
            payload[p] = ((unsigned)(r & (BROWS - 1)) << 17) | (unsigned)c;
        }
    }
}

// ---------------------------------------------------------------------------
// Pass B2: per-bucket reorder to full row order. One block per bucket:
// LDS histogram of 128 local rows -> LDS scan -> scatter cols row-sorted.
// Also emits global rowstart[n+1]. All payload traffic is L2-local.
// ---------------------------------------------------------------------------
__global__ __launch_bounds__(256) void bucket_reorder_kernel(
    const unsigned* __restrict__ bstart, const unsigned* __restrict__ payload,
    unsigned* __restrict__ cols, unsigned* __restrict__ rowstart,
    int n, int nb, unsigned e)
{
    __shared__ unsigned cnt[BROWS];
    __shared__ unsigned cur[BROWS];
    __shared__ unsigned wtot;

    const int tid = threadIdx.x;
    const int b   = blockIdx.x;
    const unsigned s0 = bstart[b], s1 = bstart[b + 1];

    if (tid < BROWS) cnt[tid] = 0u;
    __syncthreads();

    for (unsigned i = s0 + (unsigned)tid; i < s1; i += 256u)
        atomicAdd(&cnt[payload[i] >> 17], 1u);
    __syncthreads();

    // exclusive scan of cnt[0..127] (wave0: rows 0-63, wave1: rows 64-127)
    const int lane = tid & 63;
    unsigned s = (tid < BROWS) ? cnt[tid] : 0u;
    unsigned v = s;
    #pragma unroll
    for (int off = 1; off < 64; off <<= 1) {
        unsigned t2 = __shfl_up(v, off, 64);
        if (lane >= off) v += t2;
    }
    if (tid == 63) wtot = v;   // total of rows 0..63
    __syncthreads();

    if (tid < BROWS) {
        unsigned excl = (v - s) + ((tid >= 64) ? wtot : 0u);
        cur[tid] = excl;
        int r = b * BROWS + tid;
        if (r < n) rowstart[r] = s0 + excl;
    }
    if (b == nb - 1 && tid == 0) rowstart[n] = e;
    __syncthreads();

    for (unsigned i = s0 + (unsigned)tid; i < s1; i += 256u) {
        unsigned p  = payload[i];
        unsigned rl = p >> 17;
        unsigned pos = atomicAdd(&cur[rl], 1u);
        cols[s0 + pos] = p & 0x1FFFFu;
    }
}

// ---------------------------------------------------------------------------
// Pass C: row CSR SpMM, one wave per row, register accumulation, no atomics.
// ev recomputed from f1/f2; fused softmax-normalize + bias + relu.
// ---------------------------------------------------------------------------
__global__ __launch_bounds__(256) void spmm_row_kernel(
    const unsigned* __restrict__ rowstart, const unsigned* __restrict__ cols,
    const float* __restrict__ f1, const float* __restrict__ f2,
    const float* __restrict__ fts, const float* __restrict__ bias,
    float* __restrict__ out, int n)
{
    int wid  = blockIdx.x * 4 + (threadIdx.x >> 6);
    int lane = threadIdx.x & 63;
    if (wid >= n) return;

    unsigned s0 = rowstart[wid], s1 = rowstart[wid + 1];
    const float f1r = f1[wid];

    float acc = 0.f, evsum = 0.f;
    for (unsigned base = s0; base < s1; base += 64) {
        int kmax = (int)(s1 - base);
        if (kmax > 64) kmax = 64;
        int   c  = 0;
        float ev = 0.f;
        if (lane < kmax) {
            c = (int)cols[base + lane];
            float l = f1r + f2[c];
            l = (l > 0.f) ? l : NEG_SLOPE * l;
            ev = __expf(l);
        }
        evsum += ev;
        for (int j = 0; j < kmax; ++j) {
            int   cj = __shfl(c,  j, 64);
            float ej = __shfl(ev, j, 64);
            acc = fmaf(ej, fts[(size_t)cj * F_OUT + lane], acc);
        }
    }

    #pragma unroll
    for (int m = 1; m < 64; m <<= 1) evsum += __shfl_xor(evsum, m, 64);

    float v = (evsum > 0.f) ? (acc / evsum) : 0.f;
    v += bias[lane];
    out[(size_t)wid * F_OUT + lane] = fmaxf(v, 0.f);
}

// ---------------------------------------------------------------------------
extern "C" void kernel_launch(void* const* d_in, const int* in_sizes, int n_in,
                              void* d_out, int out_size, void* d_ws, size_t ws_size,
                              hipStream_t stream)
{
    const float* seq  = (const float*)d_in[0];
    const int*   er   = (const int*)  d_in[1];
    const int*   ec   = (const int*)  d_in[2];
    const float* W    = (const float*)d_in[3];
    const float* a1   = (const float*)d_in[4];
    const float* b1   = (const float*)d_in[5];
    const float* a2   = (const float*)d_in[6];
    const float* b2   = (const float*)d_in[7];
    const float* bias = (const float*)d_in[8];

    const int n  = in_sizes[0] / F_IN;
    const int e  = in_sizes[1];
    const int nb = (n + BROWS - 1) / BROWS;       // 782 for N=100000 (<=1024)
    const int eb = (e + EPB - 1) / EPB;           // 782 edge blocks

    char* ws = (char*)d_ws;
    float*    fts      = (float*)ws;    ws += (size_t)n * F_OUT * sizeof(float);   // 25.6 MB
    unsigned* payload  = (unsigned*)ws; ws += (size_t)e * sizeof(unsigned);        // 12.8 MB
    unsigned* cols     = (unsigned*)ws; ws += (size_t)e * sizeof(unsigned);        // 12.8 MB
    float*    f1       = (float*)ws;    ws += (size_t)n * sizeof(float);
    float*    f2       = (float*)ws;    ws += (size_t)n * sizeof(float);
    unsigned* cntB     = (unsigned*)ws; ws += (size_t)NREP * nb * sizeof(unsigned);
    unsigned* posB     = (unsigned*)ws; ws += (size_t)NREP * nb * sizeof(unsigned);
    unsigned* bstart   = (unsigned*)ws; ws += (size_t)(nb + 1) * sizeof(unsigned);
    unsigned* rowstart = (unsigned*)ws; ws += (size_t)(n + 1) * sizeof(unsigned);

    float* out = (float*)d_out;

    hipMemsetAsync(cntB, 0, (size_t)NREP * nb * sizeof(unsigned), stream);

    gemm_f12_kernel<<<(n + GROWS - 1) / GROWS, 256, 0, stream>>>(
        seq, W, a1, b1, a2, b2, fts, f1, f2, n);

    bucket_hist_kernel<<<eb, 256, 0, stream>>>(er, cntB, nb, e);

    bucket_scan_kernel<<<1, 1024, 0, stream>>>(cntB, posB, bstart, nb, (unsigned)e);

    bucket_scatter_kernel<<<eb, 256, 0, stream>>>(er, ec, posB, payload, nb, e);

    bucket_reorder_kernel<<<nb, 256, 0, stream>>>(
        bstart, payload, cols, rowstart, n, nb, (unsigned)e);

    spmm_row_kernel<<<(n + 3) / 4, 256, 0, stream>>>(
        rowstart, cols, f1, f2, fts, bias, out, n);
}